// Round 15
// baseline (1183.317 us; speedup 1.0000x reference)
//
#include <hip/hip_runtime.h>
#include <hip/hip_bf16.h>
#include <math.h>

typedef __attribute__((ext_vector_type(4)))  float f32x4;
typedef __attribute__((ext_vector_type(16))) float f32x16;
typedef __attribute__((ext_vector_type(8)))  short s16x8;
typedef __attribute__((ext_vector_type(4)))  short s16x4;
typedef __attribute__((ext_vector_type(4)))  int   i32x4;

#define DEVI __device__ __forceinline__

// B=4, S=4096, D=2048, H=16, DH=128, M = B*S = 16384, K = N = 2048

DEVI unsigned short f2bf(float x) {
    unsigned int u = __builtin_bit_cast(unsigned int, x);
    u += 0x7fffu + ((u >> 16) & 1u);          // RNE
    return (unsigned short)(u >> 16);
}

DEVI f32x4 mfma16(s16x8 a, s16x8 b, f32x4 c) {
    return __builtin_amdgcn_mfma_f32_16x16x32_bf16(a, b, c, 0, 0, 0);
}
DEVI f32x16 mfma32(s16x8 a, s16x8 b, f32x16 c) {
    return __builtin_amdgcn_mfma_f32_32x32x16_bf16(a, b, c, 0, 0, 0);
}
DEVI int cvtpk(float lo, float hi) {
    int r; asm("v_cvt_pk_bf16_f32 %0, %1, %2" : "=v"(r) : "v"(lo), "v"(hi)); return r;
}
DEVI void plswap(int& a, int& b) {
    asm volatile("v_permlane32_swap_b32 %0, %1" : "+v"(a), "+v"(b));
}
DEVI void gload16(const void* g, void* l) {
    __builtin_amdgcn_global_load_lds(
        (const __attribute__((address_space(1))) void*)g,
        (__attribute__((address_space(3))) void*)l, 16, 0, 0);
}

// ---------------- f32 -> bf16 flat convert (8 elems/thread/iter) ----------------
__global__ __launch_bounds__(256)
void cvt_kernel(const float* __restrict__ in, unsigned short* __restrict__ out, int n8) {
    int i = blockIdx.x * 256 + threadIdx.x;
    const int stride = gridDim.x * 256;
    for (; i < n8; i += stride) {
        f32x4 a = ((const f32x4*)in)[i * 2];
        f32x4 b = ((const f32x4*)in)[i * 2 + 1];
        s16x8 o;
#pragma unroll
        for (int e = 0; e < 4; ++e) o[e] = (short)f2bf(a[e]);
#pragma unroll
        for (int e = 0; e < 4; ++e) o[4 + e] = (short)f2bf(b[e]);
        *(s16x8*)&out[(size_t)i * 8] = o;
    }
}

// ---------------- RoPE cos/sin tables: [4096][64] f32 each ----------------
__global__ void rope_table_kernel(float* __restrict__ cosb, float* __restrict__ sinb) {
    const int s = blockIdx.x;
    const int i = threadIdx.x;                              // 0..63
    const float inv = expf(-(float)i * (9.210340371976184f / 64.0f)); // 10000^(-i/64)
    const float ang = (float)s * inv;
    cosb[s * 64 + i] = cosf(ang);
    sinb[s * 64 + i] = sinf(ang);
}

// ---------------- 256x256 counted-vmcnt GEMM (R14 state -- unchanged) ----------------
template <int EPI>
__global__ __launch_bounds__(512, 1)
void gemm256_kernel(const unsigned short* __restrict__ Ah,
                    const unsigned short* __restrict__ Wh,
                    void* __restrict__ Cp, const float* __restrict__ cosb,
                    const float* __restrict__ sinb, float oscale)
{
    constexpr int KD = 2048;
    __shared__ __align__(16) char smem[131072];

    const int tid  = threadIdx.x;
    const int lane = tid & 63;
    const int wid  = tid >> 6;
    const int wm   = wid >> 1;          // 0..3 (M group, 64 rows each)
    const int wn   = wid & 1;           // 0..1 (N group, 128 cols = one head)
    const int lr   = lane & 15;
    const int lkg  = lane >> 4;
    const int m0   = blockIdx.x * 256;
    const int n0   = blockIdx.y * 256;

    const f32x4 zero4 = {0.f, 0.f, 0.f, 0.f};
    f32x4 acc[4][8];
#pragma unroll
    for (int i = 0; i < 4; ++i)
#pragma unroll
        for (int j = 0; j < 8; ++j) acc[i][j] = zero4;

    const int rsw = (lkg ^ ((lr >> 1) & 3)) << 4;   // read-side swizzled slot

    // LDS per buf (64KB): A-kh0 @0, A-kh1 @16K, B-kh0 @32K, B-kh1 @48K
    auto stageA = [&](int b, int t, int kh) {        // 16KB: A rows 0..255
        const int k0 = t * 64 + kh * 32;
        char* dst = smem + b * 65536 + kh * 16384;
#pragma unroll
        for (int c = 0; c < 2; ++c) {
            int flat = c * 512 + tid;                // 0..1023
            int row  = flat >> 2, slot = flat & 3;
            int sg   = slot ^ ((row >> 1) & 3);
            gload16(&Ah[(size_t)(m0 + row) * KD + k0 + sg * 8], dst + flat * 16);
        }
    };
    auto stageB = [&](int b, int t, int kh) {        // 16KB: W rows 0..255
        const int k0 = t * 64 + kh * 32;
        char* dst = smem + b * 65536 + 32768 + kh * 16384;
#pragma unroll
        for (int c = 0; c < 2; ++c) {
            int flat = c * 512 + tid;
            int row  = flat >> 2, slot = flat & 3;
            int sg   = slot ^ ((row >> 1) & 3);
            gload16(&Wh[(size_t)(n0 + row) * KD + k0 + sg * 8], dst + flat * 16);
        }
    };

    auto loadA = [&](int b, int ks, s16x8 af[4]) {
        const char* Ab = smem + b * 65536 + ks * 16384;
#pragma unroll
        for (int mi = 0; mi < 4; ++mi) {
            int row = wm * 64 + mi * 16 + lr;
            af[mi] = *(const s16x8*)(Ab + row * 64 + rsw);
        }
    };
    // 16 MFMA on quadrant (ks K-half, ng N-half), af pre-loaded
    auto phaseN = [&](int b, int ks, int ng, const s16x8 af[4]) {
        const char* Bb = smem + b * 65536 + 32768 + ks * 16384;
        s16x8 bf[4];
#pragma unroll
        for (int j = 0; j < 4; ++j) {
            int row = wn * 128 + ng * 64 + j * 16 + lr;
            bf[j] = *(const s16x8*)(Bb + row * 64 + rsw);
        }
        __builtin_amdgcn_s_setprio(1);
#pragma unroll
        for (int mi = 0; mi < 4; ++mi)
#pragma unroll
            for (int j = 0; j < 4; ++j)
                acc[mi][ng * 4 + j] = mfma16(af[mi], bf[j], acc[mi][ng * 4 + j]);
        __builtin_amdgcn_s_setprio(0);
    };

    // prologue: tile 0 fully staged, one-time full drain
    stageA(0, 0, 0); stageB(0, 0, 0);
    stageA(0, 0, 1); stageB(0, 0, 1);
    asm volatile("s_waitcnt vmcnt(0)" ::: "memory");
    __builtin_amdgcn_s_barrier();

    for (int t = 0; t < 31; ++t) {
        const int b = t & 1;
        // section kh0: compute ks=0 (both N-halves); prefetch t+1 kh0
        {
            s16x8 af[4];
            stageA(b ^ 1, t + 1, 0);
            loadA(b, 0, af);
            phaseN(b, 0, 0, af);
            stageB(b ^ 1, t + 1, 0);
            phaseN(b, 0, 1, af);
        }
        asm volatile("s_waitcnt vmcnt(4)" ::: "memory");   // oldest 4 = A1(t),B1(t)
        __builtin_amdgcn_s_barrier();
        // section kh1: compute ks=1; prefetch t+1 kh1
        {
            s16x8 af[4];
            stageA(b ^ 1, t + 1, 1);
            loadA(b, 1, af);
            phaseN(b, 1, 0, af);
            stageB(b ^ 1, t + 1, 1);
            phaseN(b, 1, 1, af);
        }
        asm volatile("s_waitcnt vmcnt(4)" ::: "memory");   // oldest 4 = A0(t+1),B0(t+1)
        __builtin_amdgcn_s_barrier();
    }
    // peeled t=31 (buffer 1): kh0 landed (t=30 ledger); kh1 needs a full drain
    {
        s16x8 af[4];
        loadA(1, 0, af);
        phaseN(1, 0, 0, af); phaseN(1, 0, 1, af);
    }
    asm volatile("s_waitcnt vmcnt(0)" ::: "memory");
    __builtin_amdgcn_s_barrier();
    {
        s16x8 af[4];
        loadA(1, 1, af);
        phaseN(1, 1, 0, af); phaseN(1, 1, 1, af);
    }

    if constexpr (EPI == 0) {
        // RoPE -> bf16 [B,H,S,DH]; wave's head = 2*by + wn; pairs (nj, nj+4)
        unsigned short* Qb = (unsigned short*)Cp;
        const int h = blockIdx.y * 2 + wn;
#pragma unroll
        for (int mi = 0; mi < 4; ++mi) {
#pragma unroll
            for (int reg = 0; reg < 4; ++reg) {
                int mg = m0 + wm * 64 + mi * 16 + lkg * 4 + reg;
                int bb = mg >> 12, s = mg & 4095;
                size_t base = ((size_t)(bb * 16 + h) * 4096 + s) * 128;
#pragma unroll
                for (int nj = 0; nj < 4; ++nj) {
                    int dlo = nj * 16 + lr;                  // 0..63
                    float cv = cosb[s * 64 + dlo];
                    float sv = sinb[s * 64 + dlo];
                    float a  = acc[mi][nj][reg];
                    float b2 = acc[mi][nj + 4][reg];
                    Qb[base + dlo]      = f2bf((a * cv - b2 * sv) * oscale);
                    Qb[base + dlo + 64] = f2bf((b2 * cv + a * sv) * oscale);
                }
            }
        }
    } else if constexpr (EPI == 1) {
        // transpose -> bf16 [B,H,DH,S]; two passes, one per head (wn group)
        unsigned short* Vt = (unsigned short*)Cp;
        unsigned short* Cs = (unsigned short*)smem;        // [256][136]
        const int bb = m0 >> 12, sbase = m0 & 4095;
#pragma unroll
        for (int p = 0; p < 2; ++p) {
            __syncthreads();
            if (wn == p) {
#pragma unroll
                for (int mi = 0; mi < 4; ++mi)
#pragma unroll
                    for (int nj = 0; nj < 8; ++nj) {
                        int col = (nj & 3) * 16 + (nj >> 2) * 64 + lr;   // 0..127
#pragma unroll
                        for (int reg = 0; reg < 4; ++reg) {
                            int row = wm * 64 + mi * 16 + lkg * 4 + reg;
                            Cs[row * 136 + col] = f2bf(acc[mi][nj][reg]);
                        }
                    }
            }
            __syncthreads();
            const int h  = blockIdx.y * 2 + p;
            const int dh = tid >> 2;                  // 0..127
            const int sh = (tid & 3) * 64;
            size_t gbase = ((size_t)((bb * 16 + h) * 128 + dh)) * 4096 + sbase + sh;
#pragma unroll
            for (int j0 = 0; j0 < 8; ++j0) {
                s16x8 v;
#pragma unroll
                for (int e = 0; e < 8; ++e)
                    v[e] = (short)Cs[(sh + j0 * 8 + e) * 136 + dh];
                *(s16x8*)&Vt[gbase + j0 * 8] = v;
            }
        }
    } else {
        // f32 [M][2048] -> d_out
        float* Ob = (float*)Cp;
#pragma unroll
        for (int mi = 0; mi < 4; ++mi)
#pragma unroll
            for (int reg = 0; reg < 4; ++reg) {
                int mg = m0 + wm * 64 + mi * 16 + lkg * 4 + reg;
#pragma unroll
                for (int nj = 0; nj < 8; ++nj) {
                    int col = n0 + wn * 128 + (nj & 3) * 16 + (nj >> 2) * 64 + lr;
                    Ob[(size_t)mg * 2048 + col] = acc[mi][nj][reg];
                }
            }
    }
}

// ---------------- legacy GEMM (tier C only: f32 inputs, reg-staged) ----------------
template <bool AB16, int EPI>
__global__ __launch_bounds__(256, 2)
void gemm_kernel(const void* __restrict__ Ap, const float* __restrict__ Bw,
                 void* __restrict__ Cp, const float* __restrict__ cosb,
                 const float* __restrict__ sinb, float oscale)
{
    constexpr int KD = 2048;
    __shared__ __align__(16) unsigned short smem[20480];
    unsigned short* const As = smem;
    unsigned short* const Bs = smem + 10240;

    const int tid  = threadIdx.x;
    const int lane = tid & 63;
    const int wid  = tid >> 6;
    const int wr   = wid >> 1, wc = wid & 1;
    const int lr   = lane & 15;
    const int lkg  = lane >> 4;
    const int lk   = lkg * 8;
    const int m0   = blockIdx.x * 128;
    const int n0   = blockIdx.y * 128;

    const f32x4 zero4 = {0.f, 0.f, 0.f, 0.f};
    f32x4 acc[4][4];
#pragma unroll
    for (int i = 0; i < 4; ++i)
#pragma unroll
        for (int j = 0; j < 4; ++j) acc[i][j] = zero4;

    f32x4 aF[4], bF[4];
    s16x8 aH[2];
    const float* Af = (const float*)Ap;
    const unsigned short* AhL = (const unsigned short*)Ap;

    auto stage_load = [&](int kt) {
        const int k0 = kt * 32;
        if constexpr (!AB16) {
#pragma unroll
            for (int i = 0; i < 4; ++i) {
                int flat = i * 256 + tid;
                int r = flat >> 3, c = (flat & 7) * 4;
                aF[i] = *(const f32x4*)&Af[(size_t)(m0 + r) * KD + k0 + c];
            }
        } else {
#pragma unroll
            for (int i = 0; i < 2; ++i) {
                int flat = i * 256 + tid;
                int r = flat >> 2, c = (flat & 3) * 8;
                aH[i] = *(const s16x8*)&AhL[(size_t)(m0 + r) * KD + k0 + c];
            }
        }
#pragma unroll
        for (int i = 0; i < 4; ++i) {
            int flat = i * 256 + tid;
            int r = flat >> 3, c = (flat & 7) * 4;
            bF[i] = *(const f32x4*)&Bw[(size_t)(n0 + r) * KD + k0 + c];
        }
    };
    auto stage_write = [&](int buf) {
        unsigned short* Ab = As + buf * 5120;
        unsigned short* Bb = Bs + buf * 5120;
        if constexpr (!AB16) {
#pragma unroll
            for (int i = 0; i < 4; ++i) {
                int flat = i * 256 + tid;
                int r = flat >> 3, c = (flat & 7) * 4;
                s16x4 v;
#pragma unroll
                for (int e = 0; e < 4; ++e) v[e] = (short)f2bf(aF[i][e]);
                *(s16x4*)&Ab[r * 40 + c] = v;
            }
        } else {
#pragma unroll
            for (int i = 0; i < 2; ++i) {
                int flat = i * 256 + tid;
                int r = flat >> 2, c = (flat & 3) * 8;
                *(s16x8*)&Ab[r * 40 + c] = aH[i];
            }
        }
#pragma unroll
        for (int i = 0; i < 4; ++i) {
            int flat = i * 256 + tid;
            int r = flat >> 3, c = (flat & 7) * 4;
            s16x4 v;
#pragma unroll
            for (int e = 0; e < 4; ++e) v[e] = (short)f2bf(bF[i][e]);
            *(s16x4*)&Bb[r * 40 + c] = v;
        }
    };
    const int ncol0 = wc * 32;
    auto compute = [&](int buf) {
        const unsigned short* Ab = As + buf * 5120;
        const unsigned short* Bb = Bs + buf * 5120;
        s16x8 af[4], bf[4];
#pragma unroll
        for (int mi = 0; mi < 4; ++mi)
            af[mi] = *(const s16x8*)&Ab[(wr * 64 + mi * 16 + lr) * 40 + lk];
#pragma unroll
        for (int nj = 0; nj < 4; ++nj) {
            int nc = ncol0 + (nj & 1) * 16 + (nj >> 1) * 64;
            bf[nj] = *(const s16x8*)&Bb[(nc + lr) * 40 + lk];
        }
#pragma unroll
        for (int mi = 0; mi < 4; ++mi)
#pragma unroll
            for (int nj = 0; nj < 4; ++nj)
                acc[mi][nj] = mfma16(af[mi], bf[nj], acc[mi][nj]);
    };
    stage_load(0);
    stage_write(0);
    __syncthreads();
    for (int kt = 0; kt < 64; ++kt) {
        const int cur = kt & 1;
        if (kt < 63) stage_load(kt + 1);
        compute(cur);
        if (kt < 63) stage_write(cur ^ 1);
        __syncthreads();
    }

    if constexpr (EPI == 0) {
        unsigned short* Qb = (unsigned short*)Cp;
        const int h = blockIdx.y;
#pragma unroll
        for (int mi = 0; mi < 4; ++mi) {
#pragma unroll
            for (int reg = 0; reg < 4; ++reg) {
                int mg = m0 + wr * 64 + mi * 16 + lkg * 4 + reg;
                int bb = mg >> 12, s = mg & 4095;
                size_t base = ((size_t)(bb * 16 + h) * 4096 + s) * 128;
#pragma unroll
                for (int nj = 0; nj < 2; ++nj) {
                    int dlo = wc * 32 + nj * 16 + lr;
                    float cv = cosb[s * 64 + dlo];
                    float sv = sinb[s * 64 + dlo];
                    float a  = acc[mi][nj][reg];
                    float b2 = acc[mi][nj + 2][reg];
                    Qb[base + dlo]      = f2bf((a * cv - b2 * sv) * oscale);
                    Qb[base + dlo + 64] = f2bf((b2 * cv + a * sv) * oscale);
                }
            }
        }
    } else if constexpr (EPI == 1) {
        unsigned short* Vt = (unsigned short*)Cp;
        const int h = blockIdx.y;
        unsigned short* Cs = smem;                 // [128][136]
        __syncthreads();
#pragma unroll
        for (int mi = 0; mi < 4; ++mi)
#pragma unroll
            for (int nj = 0; nj < 4; ++nj) {
                int col = wc * 32 + (nj & 1) * 16 + (nj >> 1) * 64 + lr;
#pragma unroll
                for (int reg = 0; reg < 4; ++reg) {
                    int row = wr * 64 + mi * 16 + lkg * 4 + reg;
                    Cs[row * 136 + col] = f2bf(acc[mi][nj][reg]);
                }
            }
        __syncthreads();
        const int dh = tid >> 1;
        const int sh = (tid & 1) * 64;
        const int bb = m0 >> 12, sbase = m0 & 4095;
        size_t gbase = ((size_t)((bb * 16 + h) * 128 + dh)) * 4096 + sbase + sh;
#pragma unroll
        for (int j0 = 0; j0 < 8; ++j0) {
            s16x8 v;
#pragma unroll
            for (int e = 0; e < 8; ++e)
                v[e] = (short)Cs[(sh + j0 * 8 + e) * 136 + dh];
            *(s16x8*)&Vt[gbase + j0 * 8] = v;
        }
    } else {
        float* Ob = (float*)Cp;
#pragma unroll
        for (int mi = 0; mi < 4; ++mi)
#pragma unroll
            for (int reg = 0; reg < 4; ++reg) {
                int mg = m0 + wr * 64 + mi * 16 + lkg * 4 + reg;
#pragma unroll
                for (int nj = 0; nj < 4; ++nj) {
                    int col = n0 + wc * 32 + (nj & 1) * 16 + (nj >> 1) * 64 + lr;
                    Ob[(size_t)mg * 2048 + col] = acc[mi][nj][reg];
                }
            }
    }
}

// ---------------- Flash attention: SINGLE-BUFFER LDS (64 KB) -> 2 blocks/CU ----
// R15: R14's attn had MFMA 48% / VALU 58% at 1 block/CU (128 KB double-buffer
// was the residency limiter; VGPR=124 already fits the 4-wave/SIMD cap of 128).
// Single-buffering the K/V tile halves LDS -> 2 blocks/CU -> 4 waves/SIMD;
// the lost intra-block prefetch overlap is replaced by inter-block overlap
// (m114: co-resident blocks' MFMA and stage phases interleave on the CU).
// stage(T) -> __syncthreads (drains vmcnt: all waves' gloads landed) ->
// compute -> __syncthreads (all reads done before next overwrite).
// Everything else unchanged: unshifted softmax p=exp2(s), anti-phase wave
// groups, conflict-free (row&15)<<4 swizzle, denominator via mfma(ones,P).
__global__ __launch_bounds__(512, 2)
void attn_kernel(const unsigned short* __restrict__ Q,
                 const unsigned short* __restrict__ Kb,
                 const unsigned short* __restrict__ Vt,
                 unsigned short* __restrict__ ctx)
{
    __shared__ __align__(16) char smem[65536];   // K 32KB @0, V^T 32KB @32K

    const int tid  = threadIdx.x;
    const int lane = tid & 63;
    const int wid  = tid >> 6;        // 0..7
    const int l31  = lane & 31;
    const int h    = lane >> 5;       // 0/1
    const int qt   = blockIdx.x;      // 0..15 (256 q-rows per block)
    const int bh   = blockIdx.y;      // 0..63

    const size_t kbase  = (size_t)bh * 4096;
    const size_t vtbase = (size_t)bh * 128 * 4096;

    const size_t qrow = kbase + (size_t)qt * 256 + wid * 32 + l31;
    s16x8 qf[8];
#pragma unroll
    for (int ks = 0; ks < 8; ++ks)
        qf[ks] = *(const s16x8*)&Q[qrow * 128 + ks * 16 + h * 8];

    s16x8 ones;
#pragma unroll
    for (int e = 0; e < 8; ++e) ones[e] = (short)0x3F80;   // bf16 1.0

    const f32x16 Z16 = {0,0,0,0,0,0,0,0,0,0,0,0,0,0,0,0};
    f32x16 accO[4];
    accO[0] = Z16; accO[1] = Z16; accO[2] = Z16; accO[3] = Z16;
    f32x16 accL = Z16;

    auto stage = [&](int T) {
        const int kv0 = T * 128;
        char* kdst = smem;
        char* vdst = smem + 32768;
#pragma unroll
        for (int c = 0; c < 4; ++c) {
            int flat = c * 512 + tid;            // 0..2047
            int r    = flat >> 4;                // 0..127
            int col  = (flat & 15) * 16;
            int cs   = col ^ ((r & 15) << 4);    // 16-slot swizzle (conflict-free)
            gload16(&Kb[(kbase + kv0 + r) * 128 + (cs >> 1)], kdst + flat * 16);
            gload16(&Vt[vtbase + (size_t)r * 4096 + kv0 + (cs >> 1)], vdst + flat * 16);
        }
    };

    const int swz   = (l31 & 15) << 4;
    const int hford = wid >> 2;                  // waves 4-7 anti-phase

    for (int T = 0; T < 32; ++T) {
        stage(T);
        __syncthreads();                          // drains vmcnt: tile landed

        const char* kb = smem;
        const char* vb = smem + 32768;

#pragma unroll
        for (int hfi = 0; hfi < 2; ++hfi) {
            const int hf = hfi ^ hford;
            const char* kbh = kb + hf * 16384;
            const int   vco = hf * 128;

            f32x16 sc0 = Z16, sc1 = Z16;
            __builtin_amdgcn_s_setprio(1);
#pragma unroll
            for (int ks = 0; ks < 8; ++ks) {
                s16x8 k0 = *(const s16x8*)(kbh + ((l31 * 256 + ks * 32 + h * 16) ^ swz));
                s16x8 k1 = *(const s16x8*)(kbh + (((32 + l31) * 256 + ks * 32 + h * 16) ^ swz));
                sc0 = mfma32(k0, qf[ks], sc0);
                sc1 = mfma32(k1, qf[ks], sc1);
            }
            __builtin_amdgcn_s_setprio(0);

#pragma unroll
            for (int i = 0; i < 16; ++i) sc0[i] = exp2f(sc0[i]);
#pragma unroll
            for (int i = 0; i < 16; ++i) sc1[i] = exp2f(sc1[i]);

            s16x8 pb[4];
#pragma unroll
            for (int g = 0; g < 4; ++g) {
                const f32x16& s = (g < 2) ? sc0 : sc1;
                const int o = (g & 1) * 8;
                int a0 = cvtpk(s[o + 0], s[o + 1]);
                int a1 = cvtpk(s[o + 2], s[o + 3]);
                int b0 = cvtpk(s[o + 4], s[o + 5]);
                int b1 = cvtpk(s[o + 6], s[o + 7]);
                plswap(a0, b0); plswap(a1, b1);
                i32x4 w = {a0, a1, b0, b1};
                pb[g] = __builtin_bit_cast(s16x8, w);
            }

            __builtin_amdgcn_s_setprio(1);
#pragma unroll
            for (int ks = 0; ks < 4; ++ks) {
                accL = mfma32(ones, pb[ks], accL);
#pragma unroll
                for (int mf = 0; mf < 4; ++mf) {
                    s16x8 vf = *(const s16x8*)(vb + ((((mf * 32 + l31) * 256) + (vco + ks * 32 + h * 16)) ^ swz));
                    accO[mf] = mfma32(vf, pb[ks], accO[mf]);
                }
            }
            __builtin_amdgcn_s_setprio(0);
        }

        __syncthreads();                          // reads done before next overwrite
    }

    const float invl = 1.0f / accL[0];
    accO[0] *= invl; accO[1] *= invl; accO[2] *= invl; accO[3] *= invl;

    unsigned short* tw = (unsigned short*)smem + wid * 1088;   // [32][34] shorts
    const int bb = bh >> 4, hh = bh & 15;
    const size_t cbase = ((size_t)(bb * 4096 + qt * 256 + wid * 32 + l31)) * 2048 + hh * 128;
#pragma unroll
    for (int mf = 0; mf < 4; ++mf) {
#pragma unroll
        for (int reg = 0; reg < 16; ++reg) {
            int d = (reg & 3) + 8 * (reg >> 2) + 4 * h;
            tw[d * 34 + l31] = f2bf(accO[mf][reg]);
        }
        s16x8 o0, o1;
#pragma unroll
        for (int dd = 0; dd < 8; ++dd) {
            o0[dd] = (short)tw[(h * 16 + dd) * 34 + l31];
            o1[dd] = (short)tw[(h * 16 + 8 + dd) * 34 + l31];
        }
        *(s16x8*)&ctx[cbase + mf * 32 + h * 16]     = o0;
        *(s16x8*)&ctx[cbase + mf * 32 + h * 16 + 8] = o1;
    }
}

extern "C" void kernel_launch(void* const* d_in, const int* in_sizes, int n_in,
                              void* d_out, int out_size, void* d_ws, size_t ws_size,
                              hipStream_t stream)
{
    (void)in_sizes; (void)n_in; (void)out_size;
    const float* X  = (const float*)d_in[0];
    const float* Wq = (const float*)d_in[1];
    const float* Wk = (const float*)d_in[2];
    const float* Wv = (const float*)d_in[3];
    const float* Wo = (const float*)d_in[4];

    char* ws = (char*)d_ws;
    const size_t TBL  = 2097152;     // cos+sin tables (2 x 1 MB)
    const size_t HBUF = 67108864;    // one bf16 [B,H,S,DH]-sized buffer (64 MB)
    const size_t WBUF = 8388608;     // one bf16 [2048][2048] weight (8 MB)
    const size_t SX   = 33554432;    // X elements
    const size_t SW   = 4194304;     // W elements

    float* cosb = (float*)ws;
    float* sinb = (float*)(ws + 1048576);

    const float QSCALE = 0.12751763f;   // (1/sqrt(128)) * log2(e)
    dim3 g8(64, 8), blk8(512), blk(256);

    rope_table_kernel<<<dim3(4096), dim3(64), 0, stream>>>(cosb, sinb);

    if (ws_size >= TBL + HBUF + 4 * WBUF + 4 * HBUF) {
        // ---- tier A: everything in ws, 256x256 counted-vmcnt gemm ----
        unsigned short* Xb  = (unsigned short*)(ws + TBL);
        unsigned short* Wb0 = (unsigned short*)(ws + TBL + HBUF);
        unsigned short* Qb  = (unsigned short*)(ws + TBL + HBUF + 4 * WBUF);
        unsigned short* Kb  = Qb + SX;
        unsigned short* Vtb = Kb + SX;
        unsigned short* Cb  = Vtb + SX;
        const float* Wsrc[4] = {Wq, Wk, Wv, Wo};
        cvt_kernel<<<dim3(2048), blk, 0, stream>>>(X, Xb, (int)(SX / 8));
        for (int w = 0; w < 4; ++w)
            cvt_kernel<<<dim3(1024), blk, 0, stream>>>(Wsrc[w], Wb0 + w * SW, (int)(SW / 8));
        gemm256_kernel<0><<<g8, blk8, 0, stream>>>(Xb, Wb0,          Qb, cosb, sinb, QSCALE);
        gemm256_kernel<0><<<g8, blk8, 0, stream>>>(Xb, Wb0 + SW,     Kb, cosb, sinb, 1.0f);
        gemm256_kernel<1><<<g8, blk8, 0, stream>>>(Xb, Wb0 + 2 * SW, Vtb, cosb, sinb, 1.0f);
        attn_kernel<<<dim3(16, 64), dim3(512), 0, stream>>>(Qb, Kb, Vtb, Cb);
        gemm256_kernel<2><<<g8, blk8, 0, stream>>>(Cb, Wb0 + 3 * SW, d_out, cosb, sinb, 1.0f);
    } else if (ws_size >= TBL + HBUF + 4 * WBUF + HBUF) {
        // ---- tier B: Q,K parked in d_out; Cb shares the Xb region ----
        unsigned short* Xb  = (unsigned short*)(ws + TBL);
        unsigned short* Wb0 = (unsigned short*)(ws + TBL + HBUF);
        unsigned short* Vtb = (unsigned short*)(ws + TBL + HBUF + 4 * WBUF);
        unsigned short* Qb  = (unsigned short*)d_out;
        unsigned short* Kb  = Qb + SX;
        unsigned short* Cb  = Xb;
        const float* Wsrc[4] = {Wq, Wk, Wv, Wo};
        cvt_kernel<<<dim3(2048), blk, 0, stream>>>(X, Xb, (int)(SX / 8));
        for (int w = 0; w < 4; ++w)
            cvt_kernel<<<dim3(1024), blk, 0, stream>>>(Wsrc[w], Wb0 + w * SW, (int)(SW / 8));
        gemm256_kernel<0><<<g8, blk8, 0, stream>>>(Xb, Wb0,          Qb, cosb, sinb, QSCALE);
        gemm256_kernel<0><<<g8, blk8, 0, stream>>>(Xb, Wb0 + SW,     Kb, cosb, sinb, 1.0f);
        gemm256_kernel<1><<<g8, blk8, 0, stream>>>(Xb, Wb0 + 2 * SW, Vtb, cosb, sinb, 1.0f);
        attn_kernel<<<dim3(16, 64), dim3(512), 0, stream>>>(Qb, Kb, Vtb, Cb);
        gemm256_kernel<2><<<g8, blk8, 0, stream>>>(Cb, Wb0 + 3 * SW, d_out, cosb, sinb, 1.0f);
    } else {
        // ---- tier C: legacy path (f32 staging in-kernel), Q,K in d_out ----
        unsigned short* Vtb = (unsigned short*)(ws + TBL);
        unsigned short* Cb  = (unsigned short*)(ws + TBL + HBUF);
        unsigned short* Qb  = (unsigned short*)d_out;
        unsigned short* Kb  = Qb + SX;
        dim3 gg(128, 16);
        gemm_kernel<false, 0><<<gg, blk, 0, stream>>>(X, Wq, Qb, cosb, sinb, QSCALE);
        gemm_kernel<false, 0><<<gg, blk, 0, stream>>>(X, Wk, Kb, cosb, sinb, 1.0f);
        gemm_kernel<false, 1><<<gg, blk, 0, stream>>>(X, Wv, Vtb, cosb, sinb, 1.0f);
        attn_kernel<<<dim3(16, 64), dim3(512), 0, stream>>>(Qb, Kb, Vtb, Cb);
        gemm_kernel<true, 2><<<gg, blk, 0, stream>>>(Cb, Wo, d_out, cosb, sinb, 1.0f);
    }
}

// Round 16
// 1162.562 us; speedup vs baseline: 1.0179x; 1.0179x over previous
//
#include <hip/hip_runtime.h>
#include <hip/hip_bf16.h>
#include <math.h>

typedef __attribute__((ext_vector_type(4)))  float f32x4;
typedef __attribute__((ext_vector_type(16))) float f32x16;
typedef __attribute__((ext_vector_type(8)))  short s16x8;
typedef __attribute__((ext_vector_type(4)))  short s16x4;
typedef __attribute__((ext_vector_type(4)))  int   i32x4;

#define DEVI __device__ __forceinline__

// B=4, S=4096, D=2048, H=16, DH=128, M = B*S = 16384, K = N = 2048

DEVI unsigned short f2bf(float x) {
    unsigned int u = __builtin_bit_cast(unsigned int, x);
    u += 0x7fffu + ((u >> 16) & 1u);          // RNE
    return (unsigned short)(u >> 16);
}

DEVI f32x4 mfma16(s16x8 a, s16x8 b, f32x4 c) {
    return __builtin_amdgcn_mfma_f32_16x16x32_bf16(a, b, c, 0, 0, 0);
}
DEVI f32x16 mfma32(s16x8 a, s16x8 b, f32x16 c) {
    return __builtin_amdgcn_mfma_f32_32x32x16_bf16(a, b, c, 0, 0, 0);
}
DEVI int cvtpk(float lo, float hi) {
    int r; asm("v_cvt_pk_bf16_f32 %0, %1, %2" : "=v"(r) : "v"(lo), "v"(hi)); return r;
}
DEVI void plswap(int& a, int& b) {
    asm volatile("v_permlane32_swap_b32 %0, %1" : "+v"(a), "+v"(b));
}
DEVI void gload16(const void* g, void* l) {
    __builtin_amdgcn_global_load_lds(
        (const __attribute__((address_space(1))) void*)g,
        (__attribute__((address_space(3))) void*)l, 16, 0, 0);
}

// ---------------- f32 -> bf16 flat convert (8 elems/thread/iter) ----------------
__global__ __launch_bounds__(256)
void cvt_kernel(const float* __restrict__ in, unsigned short* __restrict__ out, int n8) {
    int i = blockIdx.x * 256 + threadIdx.x;
    const int stride = gridDim.x * 256;
    for (; i < n8; i += stride) {
        f32x4 a = ((const f32x4*)in)[i * 2];
        f32x4 b = ((const f32x4*)in)[i * 2 + 1];
        s16x8 o;
#pragma unroll
        for (int e = 0; e < 4; ++e) o[e] = (short)f2bf(a[e]);
#pragma unroll
        for (int e = 0; e < 4; ++e) o[4 + e] = (short)f2bf(b[e]);
        *(s16x8*)&out[(size_t)i * 8] = o;
    }
}

// ---------------- RoPE cos/sin tables: [4096][64] f32 each ----------------
__global__ void rope_table_kernel(float* __restrict__ cosb, float* __restrict__ sinb) {
    const int s = blockIdx.x;
    const int i = threadIdx.x;                              // 0..63
    const float inv = expf(-(float)i * (9.210340371976184f / 64.0f)); // 10000^(-i/64)
    const float ang = (float)s * inv;
    cosb[s * 64 + i] = cosf(ang);
    sinb[s * 64 + i] = sinf(ang);
}

// ---------------- 256x256 counted-vmcnt GEMM (R14 state) ----------------
// Tile 256x256, BK=64 in two K-halves; 8 waves as 4M x 2N -> per-wave 64x128.
// LDS 2buf x (A 32K + B 32K) = 128 KB, linear for global_load_lds, XOR
// swizzle slot^=(row>>1)&3 on BOTH global source and ds_read (rule #21).
// Per K-tile: 2 sync points x 32 MFMA, counted vmcnt(4) (never 0 in loop);
// A-fragments hoisted once per ks-section; last tile peeled with vmcnt(0).
template <int EPI>
__global__ __launch_bounds__(512, 1)
void gemm256_kernel(const unsigned short* __restrict__ Ah,
                    const unsigned short* __restrict__ Wh,
                    void* __restrict__ Cp, const float* __restrict__ cosb,
                    const float* __restrict__ sinb, float oscale)
{
    constexpr int KD = 2048;
    __shared__ __align__(16) char smem[131072];

    const int tid  = threadIdx.x;
    const int lane = tid & 63;
    const int wid  = tid >> 6;
    const int wm   = wid >> 1;          // 0..3 (M group, 64 rows each)
    const int wn   = wid & 1;           // 0..1 (N group, 128 cols = one head)
    const int lr   = lane & 15;
    const int lkg  = lane >> 4;
    const int m0   = blockIdx.x * 256;
    const int n0   = blockIdx.y * 256;

    const f32x4 zero4 = {0.f, 0.f, 0.f, 0.f};
    f32x4 acc[4][8];
#pragma unroll
    for (int i = 0; i < 4; ++i)
#pragma unroll
        for (int j = 0; j < 8; ++j) acc[i][j] = zero4;

    const int rsw = (lkg ^ ((lr >> 1) & 3)) << 4;   // read-side swizzled slot

    // LDS per buf (64KB): A-kh0 @0, A-kh1 @16K, B-kh0 @32K, B-kh1 @48K
    auto stageA = [&](int b, int t, int kh) {        // 16KB: A rows 0..255
        const int k0 = t * 64 + kh * 32;
        char* dst = smem + b * 65536 + kh * 16384;
#pragma unroll
        for (int c = 0; c < 2; ++c) {
            int flat = c * 512 + tid;                // 0..1023
            int row  = flat >> 2, slot = flat & 3;
            int sg   = slot ^ ((row >> 1) & 3);
            gload16(&Ah[(size_t)(m0 + row) * KD + k0 + sg * 8], dst + flat * 16);
        }
    };
    auto stageB = [&](int b, int t, int kh) {        // 16KB: W rows 0..255
        const int k0 = t * 64 + kh * 32;
        char* dst = smem + b * 65536 + 32768 + kh * 16384;
#pragma unroll
        for (int c = 0; c < 2; ++c) {
            int flat = c * 512 + tid;
            int row  = flat >> 2, slot = flat & 3;
            int sg   = slot ^ ((row >> 1) & 3);
            gload16(&Wh[(size_t)(n0 + row) * KD + k0 + sg * 8], dst + flat * 16);
        }
    };

    auto loadA = [&](int b, int ks, s16x8 af[4]) {
        const char* Ab = smem + b * 65536 + ks * 16384;
#pragma unroll
        for (int mi = 0; mi < 4; ++mi) {
            int row = wm * 64 + mi * 16 + lr;
            af[mi] = *(const s16x8*)(Ab + row * 64 + rsw);
        }
    };
    // 16 MFMA on quadrant (ks K-half, ng N-half), af pre-loaded
    auto phaseN = [&](int b, int ks, int ng, const s16x8 af[4]) {
        const char* Bb = smem + b * 65536 + 32768 + ks * 16384;
        s16x8 bf[4];
#pragma unroll
        for (int j = 0; j < 4; ++j) {
            int row = wn * 128 + ng * 64 + j * 16 + lr;
            bf[j] = *(const s16x8*)(Bb + row * 64 + rsw);
        }
        __builtin_amdgcn_s_setprio(1);
#pragma unroll
        for (int mi = 0; mi < 4; ++mi)
#pragma unroll
            for (int j = 0; j < 4; ++j)
                acc[mi][ng * 4 + j] = mfma16(af[mi], bf[j], acc[mi][ng * 4 + j]);
        __builtin_amdgcn_s_setprio(0);
    };

    // prologue: tile 0 fully staged, one-time full drain
    stageA(0, 0, 0); stageB(0, 0, 0);
    stageA(0, 0, 1); stageB(0, 0, 1);
    asm volatile("s_waitcnt vmcnt(0)" ::: "memory");
    __builtin_amdgcn_s_barrier();

    for (int t = 0; t < 31; ++t) {
        const int b = t & 1;
        // section kh0: compute ks=0 (both N-halves); prefetch t+1 kh0
        {
            s16x8 af[4];
            stageA(b ^ 1, t + 1, 0);
            loadA(b, 0, af);
            phaseN(b, 0, 0, af);
            stageB(b ^ 1, t + 1, 0);
            phaseN(b, 0, 1, af);
        }
        asm volatile("s_waitcnt vmcnt(4)" ::: "memory");   // oldest 4 = A1(t),B1(t)
        __builtin_amdgcn_s_barrier();
        // section kh1: compute ks=1; prefetch t+1 kh1
        {
            s16x8 af[4];
            stageA(b ^ 1, t + 1, 1);
            loadA(b, 1, af);
            phaseN(b, 1, 0, af);
            stageB(b ^ 1, t + 1, 1);
            phaseN(b, 1, 1, af);
        }
        asm volatile("s_waitcnt vmcnt(4)" ::: "memory");   // oldest 4 = A0(t+1),B0(t+1)
        __builtin_amdgcn_s_barrier();
    }
    // peeled t=31 (buffer 1): kh0 landed (t=30 ledger); kh1 needs a full drain
    {
        s16x8 af[4];
        loadA(1, 0, af);
        phaseN(1, 0, 0, af); phaseN(1, 0, 1, af);
    }
    asm volatile("s_waitcnt vmcnt(0)" ::: "memory");
    __builtin_amdgcn_s_barrier();
    {
        s16x8 af[4];
        loadA(1, 1, af);
        phaseN(1, 1, 0, af); phaseN(1, 1, 1, af);
    }

    if constexpr (EPI == 0) {
        // RoPE -> bf16 [B,H,S,DH]; wave's head = 2*by + wn; pairs (nj, nj+4)
        unsigned short* Qb = (unsigned short*)Cp;
        const int h = blockIdx.y * 2 + wn;
#pragma unroll
        for (int mi = 0; mi < 4; ++mi) {
#pragma unroll
            for (int reg = 0; reg < 4; ++reg) {
                int mg = m0 + wm * 64 + mi * 16 + lkg * 4 + reg;
                int bb = mg >> 12, s = mg & 4095;
                size_t base = ((size_t)(bb * 16 + h) * 4096 + s) * 128;
#pragma unroll
                for (int nj = 0; nj < 4; ++nj) {
                    int dlo = nj * 16 + lr;                  // 0..63
                    float cv = cosb[s * 64 + dlo];
                    float sv = sinb[s * 64 + dlo];
                    float a  = acc[mi][nj][reg];
                    float b2 = acc[mi][nj + 4][reg];
                    Qb[base + dlo]      = f2bf((a * cv - b2 * sv) * oscale);
                    Qb[base + dlo + 64] = f2bf((b2 * cv + a * sv) * oscale);
                }
            }
        }
    } else if constexpr (EPI == 1) {
        // transpose -> bf16 [B,H,DH,S]; two passes, one per head (wn group)
        unsigned short* Vt = (unsigned short*)Cp;
        unsigned short* Cs = (unsigned short*)smem;        // [256][136]
        const int bb = m0 >> 12, sbase = m0 & 4095;
#pragma unroll
        for (int p = 0; p < 2; ++p) {
            __syncthreads();
            if (wn == p) {
#pragma unroll
                for (int mi = 0; mi < 4; ++mi)
#pragma unroll
                    for (int nj = 0; nj < 8; ++nj) {
                        int col = (nj & 3) * 16 + (nj >> 2) * 64 + lr;   // 0..127
#pragma unroll
                        for (int reg = 0; reg < 4; ++reg) {
                            int row = wm * 64 + mi * 16 + lkg * 4 + reg;
                            Cs[row * 136 + col] = f2bf(acc[mi][nj][reg]);
                        }
                    }
            }
            __syncthreads();
            const int h  = blockIdx.y * 2 + p;
            const int dh = tid >> 2;                  // 0..127
            const int sh = (tid & 3) * 64;
            size_t gbase = ((size_t)((bb * 16 + h) * 128 + dh)) * 4096 + sbase + sh;
#pragma unroll
            for (int j0 = 0; j0 < 8; ++j0) {
                s16x8 v;
#pragma unroll
                for (int e = 0; e < 8; ++e)
                    v[e] = (short)Cs[(sh + j0 * 8 + e) * 136 + dh];
                *(s16x8*)&Vt[gbase + j0 * 8] = v;
            }
        }
    } else {
        // f32 [M][2048] -> d_out
        float* Ob = (float*)Cp;
#pragma unroll
        for (int mi = 0; mi < 4; ++mi)
#pragma unroll
            for (int reg = 0; reg < 4; ++reg) {
                int mg = m0 + wm * 64 + mi * 16 + lkg * 4 + reg;
#pragma unroll
                for (int nj = 0; nj < 8; ++nj) {
                    int col = n0 + wn * 128 + (nj & 3) * 16 + (nj >> 2) * 64 + lr;
                    Ob[(size_t)mg * 2048 + col] = acc[mi][nj][reg];
                }
            }
    }
}

// ---------------- legacy GEMM (tier C only: f32 inputs, reg-staged) ----------------
template <bool AB16, int EPI>
__global__ __launch_bounds__(256, 2)
void gemm_kernel(const void* __restrict__ Ap, const float* __restrict__ Bw,
                 void* __restrict__ Cp, const float* __restrict__ cosb,
                 const float* __restrict__ sinb, float oscale)
{
    constexpr int KD = 2048;
    __shared__ __align__(16) unsigned short smem[20480];
    unsigned short* const As = smem;
    unsigned short* const Bs = smem + 10240;

    const int tid  = threadIdx.x;
    const int lane = tid & 63;
    const int wid  = tid >> 6;
    const int wr   = wid >> 1, wc = wid & 1;
    const int lr   = lane & 15;
    const int lkg  = lane >> 4;
    const int lk   = lkg * 8;
    const int m0   = blockIdx.x * 128;
    const int n0   = blockIdx.y * 128;

    const f32x4 zero4 = {0.f, 0.f, 0.f, 0.f};
    f32x4 acc[4][4];
#pragma unroll
    for (int i = 0; i < 4; ++i)
#pragma unroll
        for (int j = 0; j < 4; ++j) acc[i][j] = zero4;

    f32x4 aF[4], bF[4];
    s16x8 aH[2];
    const float* Af = (const float*)Ap;
    const unsigned short* AhL = (const unsigned short*)Ap;

    auto stage_load = [&](int kt) {
        const int k0 = kt * 32;
        if constexpr (!AB16) {
#pragma unroll
            for (int i = 0; i < 4; ++i) {
                int flat = i * 256 + tid;
                int r = flat >> 3, c = (flat & 7) * 4;
                aF[i] = *(const f32x4*)&Af[(size_t)(m0 + r) * KD + k0 + c];
            }
        } else {
#pragma unroll
            for (int i = 0; i < 2; ++i) {
                int flat = i * 256 + tid;
                int r = flat >> 2, c = (flat & 3) * 8;
                aH[i] = *(const s16x8*)&AhL[(size_t)(m0 + r) * KD + k0 + c];
            }
        }
#pragma unroll
        for (int i = 0; i < 4; ++i) {
            int flat = i * 256 + tid;
            int r = flat >> 3, c = (flat & 7) * 4;
            bF[i] = *(const f32x4*)&Bw[(size_t)(n0 + r) * KD + k0 + c];
        }
    };
    auto stage_write = [&](int buf) {
        unsigned short* Ab = As + buf * 5120;
        unsigned short* Bb = Bs + buf * 5120;
        if constexpr (!AB16) {
#pragma unroll
            for (int i = 0; i < 4; ++i) {
                int flat = i * 256 + tid;
                int r = flat >> 3, c = (flat & 7) * 4;
                s16x4 v;
#pragma unroll
                for (int e = 0; e < 4; ++e) v[e] = (short)f2bf(aF[i][e]);
                *(s16x4*)&Ab[r * 40 + c] = v;
            }
        } else {
#pragma unroll
            for (int i = 0; i < 2; ++i) {
                int flat = i * 256 + tid;
                int r = flat >> 2, c = (flat & 3) * 8;
                *(s16x8*)&Ab[r * 40 + c] = aH[i];
            }
        }
#pragma unroll
        for (int i = 0; i < 4; ++i) {
            int flat = i * 256 + tid;
            int r = flat >> 3, c = (flat & 7) * 4;
            s16x4 v;
#pragma unroll
            for (int e = 0; e < 4; ++e) v[e] = (short)f2bf(bF[i][e]);
            *(s16x4*)&Bb[r * 40 + c] = v;
        }
    };
    const int ncol0 = wc * 32;
    auto compute = [&](int buf) {
        const unsigned short* Ab = As + buf * 5120;
        const unsigned short* Bb = Bs + buf * 5120;
        s16x8 af[4], bf[4];
#pragma unroll
        for (int mi = 0; mi < 4; ++mi)
            af[mi] = *(const s16x8*)&Ab[(wr * 64 + mi * 16 + lr) * 40 + lk];
#pragma unroll
        for (int nj = 0; nj < 4; ++nj) {
            int nc = ncol0 + (nj & 1) * 16 + (nj >> 1) * 64;
            bf[nj] = *(const s16x8*)&Bb[(nc + lr) * 40 + lk];
        }
#pragma unroll
        for (int mi = 0; mi < 4; ++mi)
#pragma unroll
            for (int nj = 0; nj < 4; ++nj)
                acc[mi][nj] = mfma16(af[mi], bf[nj], acc[mi][nj]);
    };
    stage_load(0);
    stage_write(0);
    __syncthreads();
    for (int kt = 0; kt < 64; ++kt) {
        const int cur = kt & 1;
        if (kt < 63) stage_load(kt + 1);
        compute(cur);
        if (kt < 63) stage_write(cur ^ 1);
        __syncthreads();
    }

    if constexpr (EPI == 0) {
        unsigned short* Qb = (unsigned short*)Cp;
        const int h = blockIdx.y;
#pragma unroll
        for (int mi = 0; mi < 4; ++mi) {
#pragma unroll
            for (int reg = 0; reg < 4; ++reg) {
                int mg = m0 + wr * 64 + mi * 16 + lkg * 4 + reg;
                int bb = mg >> 12, s = mg & 4095;
                size_t base = ((size_t)(bb * 16 + h) * 4096 + s) * 128;
#pragma unroll
                for (int nj = 0; nj < 2; ++nj) {
                    int dlo = wc * 32 + nj * 16 + lr;
                    float cv = cosb[s * 64 + dlo];
                    float sv = sinb[s * 64 + dlo];
                    float a  = acc[mi][nj][reg];
                    float b2 = acc[mi][nj + 2][reg];
                    Qb[base + dlo]      = f2bf((a * cv - b2 * sv) * oscale);
                    Qb[base + dlo + 64] = f2bf((b2 * cv + a * sv) * oscale);
                }
            }
        }
    } else if constexpr (EPI == 1) {
        unsigned short* Vt = (unsigned short*)Cp;
        const int h = blockIdx.y;
        unsigned short* Cs = smem;                 // [128][136]
        __syncthreads();
#pragma unroll
        for (int mi = 0; mi < 4; ++mi)
#pragma unroll
            for (int nj = 0; nj < 4; ++nj) {
                int col = wc * 32 + (nj & 1) * 16 + (nj >> 1) * 64 + lr;
#pragma unroll
                for (int reg = 0; reg < 4; ++reg) {
                    int row = wr * 64 + mi * 16 + lkg * 4 + reg;
                    Cs[row * 136 + col] = f2bf(acc[mi][nj][reg]);
                }
            }
        __syncthreads();
        const int dh = tid >> 1;
        const int sh = (tid & 1) * 64;
        const int bb = m0 >> 12, sbase = m0 & 4095;
        size_t gbase = ((size_t)((bb * 16 + h) * 128 + dh)) * 4096 + sbase + sh;
#pragma unroll
        for (int j0 = 0; j0 < 8; ++j0) {
            s16x8 v;
#pragma unroll
            for (int e = 0; e < 8; ++e)
                v[e] = (short)Cs[(sh + j0 * 8 + e) * 136 + dh];
            *(s16x8*)&Vt[gbase + j0 * 8] = v;
        }
    } else {
        float* Ob = (float*)Cp;
#pragma unroll
        for (int mi = 0; mi < 4; ++mi)
#pragma unroll
            for (int reg = 0; reg < 4; ++reg) {
                int mg = m0 + wr * 64 + mi * 16 + lkg * 4 + reg;
#pragma unroll
                for (int nj = 0; nj < 4; ++nj) {
                    int col = n0 + wc * 32 + (nj & 1) * 16 + (nj >> 1) * 64 + lr;
                    Ob[(size_t)mg * 2048 + col] = acc[mi][nj][reg];
                }
            }
    }
}

// ---------------- Flash attention (R14/R10 state -- double-buffered, best) ----
// 8 waves x 32 q-rows, 32x32 MFMA, unshifted softmax p=exp2(s) (QSCALE folds
// the 1/sqrt(128)*log2e into Q; scores bounded, f32-exact; accL normalizes).
// Anti-phase wave groups (waves 4-7 process kv-halves in reverse order) so
// SIMD co-residents overlap QK/PV MFMA with exp2/pack VALU.
// K/V^T double-buffered in LDS (128 KB) via global_load_lds, pre-swizzled
// source; (row&15)<<4 swizzle measured SQ_LDS_BANK_CONFLICT = 0.
// VGPR law (R4/R6/R9/R15): demand >~124 spills (WRITE inflates) -- keep lean;
// single-buffer/2-block variant FAILED (R15: 4 waves/SIMD x 128 VGPR = 512 =
// exactly the file, granularity blocks residency; occupancy stayed 1 blk/CU).
__global__ __launch_bounds__(512, 2)
void attn_kernel(const unsigned short* __restrict__ Q,
                 const unsigned short* __restrict__ Kb,
                 const unsigned short* __restrict__ Vt,
                 unsigned short* __restrict__ ctx)
{
    __shared__ __align__(16) char smem[131072];   // 2 x (32KB K + 32KB V^T)

    const int tid  = threadIdx.x;
    const int lane = tid & 63;
    const int wid  = tid >> 6;        // 0..7
    const int l31  = lane & 31;
    const int h    = lane >> 5;       // 0/1
    const int qt   = blockIdx.x;      // 0..15 (256 q-rows per block)
    const int bh   = blockIdx.y;      // 0..63

    const size_t kbase  = (size_t)bh * 4096;
    const size_t vtbase = (size_t)bh * 128 * 4096;

    const size_t qrow = kbase + (size_t)qt * 256 + wid * 32 + l31;
    s16x8 qf[8];
#pragma unroll
    for (int ks = 0; ks < 8; ++ks)
        qf[ks] = *(const s16x8*)&Q[qrow * 128 + ks * 16 + h * 8];

    s16x8 ones;
#pragma unroll
    for (int e = 0; e < 8; ++e) ones[e] = (short)0x3F80;   // bf16 1.0

    const f32x16 Z16 = {0,0,0,0,0,0,0,0,0,0,0,0,0,0,0,0};
    f32x16 accO[4];
    accO[0] = Z16; accO[1] = Z16; accO[2] = Z16; accO[3] = Z16;
    f32x16 accL = Z16;

    auto stage = [&](int buf, int T) {
        const int kv0 = T * 128;
        char* kdst = smem + buf * 65536;
        char* vdst = kdst + 32768;
#pragma unroll
        for (int c = 0; c < 4; ++c) {
            int flat = c * 512 + tid;            // 0..2047
            int r    = flat >> 4;                // 0..127
            int col  = (flat & 15) * 16;
            int cs   = col ^ ((r & 15) << 4);    // 16-slot swizzle (conflict-free)
            gload16(&Kb[(kbase + kv0 + r) * 128 + (cs >> 1)], kdst + flat * 16);
            gload16(&Vt[vtbase + (size_t)r * 4096 + kv0 + (cs >> 1)], vdst + flat * 16);
        }
    };

    const int swz   = (l31 & 15) << 4;
    const int hford = wid >> 2;                  // waves 4-7 anti-phase

    stage(0, 0);
    __syncthreads();

    for (int T = 0; T < 32; ++T) {
        const int buf = T & 1;
        if (T < 31) stage(buf ^ 1, T + 1);

        const char* kb = smem + buf * 65536;
        const char* vb = kb + 32768;

#pragma unroll
        for (int hfi = 0; hfi < 2; ++hfi) {
            const int hf = hfi ^ hford;
            const char* kbh = kb + hf * 16384;
            const int   vco = hf * 128;

            f32x16 sc0 = Z16, sc1 = Z16;
            __builtin_amdgcn_s_setprio(1);
#pragma unroll
            for (int ks = 0; ks < 8; ++ks) {
                s16x8 k0 = *(const s16x8*)(kbh + ((l31 * 256 + ks * 32 + h * 16) ^ swz));
                s16x8 k1 = *(const s16x8*)(kbh + (((32 + l31) * 256 + ks * 32 + h * 16) ^ swz));
                sc0 = mfma32(k0, qf[ks], sc0);
                sc1 = mfma32(k1, qf[ks], sc1);
            }
            __builtin_amdgcn_s_setprio(0);

#pragma unroll
            for (int i = 0; i < 16; ++i) sc0[i] = exp2f(sc0[i]);
#pragma unroll
            for (int i = 0; i < 16; ++i) sc1[i] = exp2f(sc1[i]);

            s16x8 pb[4];
#pragma unroll
            for (int g = 0; g < 4; ++g) {
                const f32x16& s = (g < 2) ? sc0 : sc1;
                const int o = (g & 1) * 8;
                int a0 = cvtpk(s[o + 0], s[o + 1]);
                int a1 = cvtpk(s[o + 2], s[o + 3]);
                int b0 = cvtpk(s[o + 4], s[o + 5]);
                int b1 = cvtpk(s[o + 6], s[o + 7]);
                plswap(a0, b0); plswap(a1, b1);
                i32x4 w = {a0, a1, b0, b1};
                pb[g] = __builtin_bit_cast(s16x8, w);
            }

            __builtin_amdgcn_s_setprio(1);
#pragma unroll
            for (int ks = 0; ks < 4; ++ks) {
                accL = mfma32(ones, pb[ks], accL);
#pragma unroll
                for (int mf = 0; mf < 4; ++mf) {
                    s16x8 vf = *(const s16x8*)(vb + ((((mf * 32 + l31) * 256) + (vco + ks * 32 + h * 16)) ^ swz));
                    accO[mf] = mfma32(vf, pb[ks], accO[mf]);
                }
            }
            __builtin_amdgcn_s_setprio(0);
        }

        __syncthreads();
    }

    const float invl = 1.0f / accL[0];
    accO[0] *= invl; accO[1] *= invl; accO[2] *= invl; accO[3] *= invl;

    unsigned short* tw = (unsigned short*)smem + wid * 1088;   // [32][34] shorts
    const int bb = bh >> 4, hh = bh & 15;
    const size_t cbase = ((size_t)(bb * 4096 + qt * 256 + wid * 32 + l31)) * 2048 + hh * 128;
#pragma unroll
    for (int mf = 0; mf < 4; ++mf) {
#pragma unroll
        for (int reg = 0; reg < 16; ++reg) {
            int d = (reg & 3) + 8 * (reg >> 2) + 4 * h;
            tw[d * 34 + l31] = f2bf(accO[mf][reg]);
        }
        s16x8 o0, o1;
#pragma unroll
        for (int dd = 0; dd < 8; ++dd) {
            o0[dd] = (short)tw[(h * 16 + dd) * 34 + l31];
            o1[dd] = (short)tw[(h * 16 + 8 + dd) * 34 + l31];
        }
        *(s16x8*)&ctx[cbase + mf * 32 + h * 16]     = o0;
        *(s16x8*)&ctx[cbase + mf * 32 + h * 16 + 8] = o1;
    }
}

extern "C" void kernel_launch(void* const* d_in, const int* in_sizes, int n_in,
                              void* d_out, int out_size, void* d_ws, size_t ws_size,
                              hipStream_t stream)
{
    (void)in_sizes; (void)n_in; (void)out_size;
    const float* X  = (const float*)d_in[0];
    const float* Wq = (const float*)d_in[1];
    const float* Wk = (const float*)d_in[2];
    const float* Wv = (const float*)d_in[3];
    const float* Wo = (const float*)d_in[4];

    char* ws = (char*)d_ws;
    const size_t TBL  = 2097152;     // cos+sin tables (2 x 1 MB)
    const size_t HBUF = 67108864;    // one bf16 [B,H,S,DH]-sized buffer (64 MB)
    const size_t WBUF = 8388608;     // one bf16 [2048][2048] weight (8 MB)
    const size_t SX   = 33554432;    // X elements
    const size_t SW   = 4194304;     // W elements

    float* cosb = (float*)ws;
    float* sinb = (float*)(ws + 1048576);

    const float QSCALE = 0.12751763f;   // (1/sqrt(128)) * log2(e)
    dim3 g8(64, 8), blk8(512), blk(256);

    rope_table_kernel<<<dim3(4096), dim3(64), 0, stream>>>(cosb, sinb);

    if (ws_size >= TBL + HBUF + 4 * WBUF + 4 * HBUF) {
        // ---- tier A: everything in ws, 256x256 counted-vmcnt gemm ----
        unsigned short* Xb  = (unsigned short*)(ws + TBL);
        unsigned short* Wb0 = (unsigned short*)(ws + TBL + HBUF);
        unsigned short* Qb  = (unsigned short*)(ws + TBL + HBUF + 4 * WBUF);
        unsigned short* Kb  = Qb + SX;
        unsigned short* Vtb = Kb + SX;
        unsigned short* Cb  = Vtb + SX;
        const float* Wsrc[4] = {Wq, Wk, Wv, Wo};
        cvt_kernel<<<dim3(2048), blk, 0, stream>>>(X, Xb, (int)(SX / 8));
        for (int w = 0; w < 4; ++w)
            cvt_kernel<<<dim3(1024), blk, 0, stream>>>(Wsrc[w], Wb0 + w * SW, (int)(SW / 8));
        gemm256_kernel<0><<<g8, blk8, 0, stream>>>(Xb, Wb0,          Qb, cosb, sinb, QSCALE);
        gemm256_kernel<0><<<g8, blk8, 0, stream>>>(Xb, Wb0 + SW,     Kb, cosb, sinb, 1.0f);
        gemm256_kernel<1><<<g8, blk8, 0, stream>>>(Xb, Wb0 + 2 * SW, Vtb, cosb, sinb, 1.0f);
        attn_kernel<<<dim3(16, 64), dim3(512), 0, stream>>>(Qb, Kb, Vtb, Cb);
        gemm256_kernel<2><<<g8, blk8, 0, stream>>>(Cb, Wb0 + 3 * SW, d_out, cosb, sinb, 1.0f);
    } else if (ws_size >= TBL + HBUF + 4 * WBUF + HBUF) {
        // ---- tier B: Q,K parked in d_out; Cb shares the Xb region ----
        unsigned short* Xb  = (unsigned short*)(ws + TBL);
        unsigned short* Wb0 = (unsigned short*)(ws + TBL + HBUF);
        unsigned short* Vtb = (unsigned short*)(ws + TBL + HBUF + 4 * WBUF);
        unsigned short* Qb  = (unsigned short*)d_out;
        unsigned short* Kb  = Qb + SX;
        unsigned short* Cb  = Xb;
        const float* Wsrc[4] = {Wq, Wk, Wv, Wo};
        cvt_kernel<<<dim3(2048), blk, 0, stream>>>(X, Xb, (int)(SX / 8));
        for (int w = 0; w < 4; ++w)
            cvt_kernel<<<dim3(1024), blk, 0, stream>>>(Wsrc[w], Wb0 + w * SW, (int)(SW / 8));
        gemm256_kernel<0><<<g8, blk8, 0, stream>>>(Xb, Wb0,          Qb, cosb, sinb, QSCALE);
        gemm256_kernel<0><<<g8, blk8, 0, stream>>>(Xb, Wb0 + SW,     Kb, cosb, sinb, 1.0f);
        gemm256_kernel<1><<<g8, blk8, 0, stream>>>(Xb, Wb0 + 2 * SW, Vtb, cosb, sinb, 1.0f);
        attn_kernel<<<dim3(16, 64), dim3(512), 0, stream>>>(Qb, Kb, Vtb, Cb);
        gemm256_kernel<2><<<g8, blk8, 0, stream>>>(Cb, Wb0 + 3 * SW, d_out, cosb, sinb, 1.0f);
    } else {
        // ---- tier C: legacy path (f32 staging in-kernel), Q,K in d_out ----
        unsigned short* Vtb = (unsigned short*)(ws + TBL);
        unsigned short* Cb  = (unsigned short*)(ws + TBL + HBUF);
        unsigned short* Qb  = (unsigned short*)d_out;
        unsigned short* Kb  = Qb + SX;
        dim3 gg(128, 16);
        gemm_kernel<false, 0><<<gg, blk, 0, stream>>>(X, Wq, Qb, cosb, sinb, QSCALE);
        gemm_kernel<false, 0><<<gg, blk, 0, stream>>>(X, Wk, Kb, cosb, sinb, 1.0f);
        gemm_kernel<false, 1><<<gg, blk, 0, stream>>>(X, Wv, Vtb, cosb, sinb, 1.0f);
        attn_kernel<<<dim3(16, 64), dim3(512), 0, stream>>>(Qb, Kb, Vtb, Cb);
        gemm_kernel<true, 2><<<gg, blk, 0, stream>>>(Cb, Wo, d_out, cosb, sinb, 1.0f);
    }
}